// Round 1
// baseline (1146.828 us; speedup 1.0000x reference)
//
#include <hip/hip_runtime.h>

typedef unsigned short u16;
typedef unsigned int u32;
typedef float f32x4v __attribute__((ext_vector_type(4)));
typedef __bf16 bf16x8 __attribute__((ext_vector_type(8)));

__device__ __forceinline__ u16 f2bf(float f) {
  u32 u = __builtin_bit_cast(u32, f);
  u32 r = (u + 0x7FFFu + ((u >> 16) & 1u)) >> 16;  // RNE
  return (u16)r;
}
__device__ __forceinline__ float bf2f(u16 h) {
  return __builtin_bit_cast(float, (u32)h << 16);
}

// ---------------------------------------------------------------------------
// Generic MFMA GEMM:  C[m][n] = (sum_k A[m][k]*B[n][k] + bias[m]) * scale
// A: fp32 [M,K] row-major (K contiguous), converted to bf16 in staging.
// B: bf16 [N,K] row-major (K contiguous).
// 128x128 tile, BK=32, 4 waves of 64x64, v_mfma_f32_16x16x32_bf16.
// ---------------------------------------------------------------------------
template <bool HAS_BIAS, bool OUT_BF16>
__global__ __launch_bounds__(256) void gemm_kernel(
    const float* __restrict__ A, const u16* __restrict__ B,
    void* __restrict__ C, const float* __restrict__ bias,
    int M, int N, int K, long strA, long strB, long strC, float scale)
{
  constexpr int BM = 128, BN = 128, BK = 32, PAD = 8;
  __shared__ u16 sA[BM][BK + PAD];
  __shared__ u16 sB[BN][BK + PAD];
  const int t = threadIdx.x;
  const int lane = t & 63;
  const int wave = t >> 6;
  const int wr = (wave >> 1) * 64;   // wave row offset in tile
  const int wc = (wave & 1) * 64;    // wave col offset in tile
  const int m0 = blockIdx.x * BM, n0 = blockIdx.y * BN;
  A += (long)blockIdx.z * strA;
  B += (long)blockIdx.z * strB;
  const int srow = t >> 1;           // 0..127: one LDS row per thread pair
  const int sk = (t & 1) * 16;       // 16 K-elements per thread
  const int lr = lane & 15;
  const int lk = (lane >> 4) * 8;
  f32x4v acc[4][4] = {};

  for (int k0 = 0; k0 < K; k0 += BK) {
    __syncthreads();
    { // stage A (fp32 -> bf16)
      u16 us[16];
      const int gr = m0 + srow;
      if (gr < M) {
        const float4* src = (const float4*)(A + (long)gr * K + (k0 + sk));
        #pragma unroll
        for (int q = 0; q < 4; ++q) {
          float4 v = src[q];
          us[4*q+0] = f2bf(v.x); us[4*q+1] = f2bf(v.y);
          us[4*q+2] = f2bf(v.z); us[4*q+3] = f2bf(v.w);
        }
      } else {
        #pragma unroll
        for (int q = 0; q < 16; ++q) us[q] = 0;
      }
      *(uint4*)&sA[srow][sk]     = *(uint4*)&us[0];
      *(uint4*)&sA[srow][sk + 8] = *(uint4*)&us[8];
    }
    { // stage B (bf16 pass-through)
      const int gn = n0 + srow;
      uint4 v0 = make_uint4(0,0,0,0), v1 = make_uint4(0,0,0,0);
      if (gn < N) {
        const uint4* src = (const uint4*)(B + (long)gn * K + (k0 + sk));
        v0 = src[0]; v1 = src[1];
      }
      *(uint4*)&sB[srow][sk]     = v0;
      *(uint4*)&sB[srow][sk + 8] = v1;
    }
    __syncthreads();

    bf16x8 af[4], bf[4];
    #pragma unroll
    for (int i = 0; i < 4; ++i) af[i] = *(const bf16x8*)&sA[wr + i*16 + lr][lk];
    #pragma unroll
    for (int j = 0; j < 4; ++j) bf[j] = *(const bf16x8*)&sB[wc + j*16 + lr][lk];
    #pragma unroll
    for (int i = 0; i < 4; ++i) {
      #pragma unroll
      for (int j = 0; j < 4; ++j) {
        acc[i][j] = __builtin_amdgcn_mfma_f32_16x16x32_bf16(af[i], bf[j], acc[i][j], 0, 0, 0);
      }
    }
  }

  // epilogue: D lane l reg r -> row=(l>>4)*4+r, col=l&15  [measured m89/m91]
  const long cbase = (long)blockIdx.z * strC;
  const int lq = (lane >> 4) * 4;
  #pragma unroll
  for (int i = 0; i < 4; ++i) {
    #pragma unroll
    for (int r = 0; r < 4; ++r) {
      const int row = m0 + wr + i*16 + lq + r;
      if (row >= M) continue;
      const float bv = HAS_BIAS ? bias[row] : 0.0f;
      #pragma unroll
      for (int j = 0; j < 4; ++j) {
        const int col = n0 + wc + j*16 + lr;
        if (col < N) {
          const float v = (acc[i][j][r] + bv) * scale;
          if constexpr (OUT_BF16)
            ((u16*)C)[cbase + (long)row * N + col] = f2bf(v);
          else
            ((float*)C)[cbase + (long)row * N + col] = v;
        }
      }
    }
  }
}

// ---------------------------------------------------------------------------
// Transpose + optional convert: out[c][r] = in[r][c]   (per z-slice)
// ---------------------------------------------------------------------------
template <bool OUT_BF16>
__global__ __launch_bounds__(256) void transpose_k(
    const float* __restrict__ in, void* __restrict__ out,
    int R, int C, long strIn, long strOut)
{
  __shared__ float tile[32][33];
  in += (long)blockIdx.z * strIn;
  const int c0 = blockIdx.x * 32, r0 = blockIdx.y * 32;
  const int tx = threadIdx.x & 31, ty = threadIdx.x >> 5;
  for (int i = ty; i < 32; i += 8) {
    const int r = r0 + i, c = c0 + tx;
    tile[i][tx] = (r < R && c < C) ? in[(long)r * C + c] : 0.0f;
  }
  __syncthreads();
  for (int i = ty; i < 32; i += 8) {
    const int c = c0 + i, r = r0 + tx;
    if (c < C && r < R) {
      const long o = (long)blockIdx.z * strOut + (long)c * R + r;
      if constexpr (OUT_BF16) ((u16*)out)[o] = f2bf(tile[tx][i]);
      else                    ((float*)out)[o] = tile[tx][i];
    }
  }
}

// ---------------------------------------------------------------------------
// im2col for 3x3 SAME conv on 28x28: dst[im][p][ci*9+ky*3+kx] (bf16)
// ---------------------------------------------------------------------------
__global__ __launch_bounds__(256) void im2col_3x3(
    const float* __restrict__ src, u16* __restrict__ dst, int Cin, int nImg)
{
  const long total = (long)nImg * 784 * Cin * 9;
  const long idx = (long)blockIdx.x * 256 + threadIdx.x;
  if (idx >= total) return;
  const int Kd = Cin * 9;
  const int kk = (int)(idx % Kd);
  const long rest = idx / Kd;
  const int p = (int)(rest % 784);
  const int im = (int)(rest / 784);
  const int ci = kk / 9, tap = kk % 9;
  const int y = p / 28 + tap / 3 - 1, x = p % 28 + tap % 3 - 1;
  float v = 0.0f;
  if ((unsigned)y < 28u && (unsigned)x < 28u)
    v = src[((long)im * Cin + ci) * 784 + y * 28 + x];
  dst[idx] = f2bf(v);
}

// im2col over concat([readout(512ch), h(256ch)]) for the transform conv
__global__ __launch_bounds__(256) void im2col_concat(
    const float* __restrict__ ro,   // [B][1536][784]
    const float* __restrict__ h,    // [B*3][256][784]
    u16* __restrict__ dst)          // [6][784][6912]
{
  const long total = 6L * 784 * 6912;
  const long idx = (long)blockIdx.x * 256 + threadIdx.x;
  if (idx >= total) return;
  const int kk = (int)(idx % 6912);
  const long rest = idx / 6912;
  const int p = (int)(rest % 784);
  const int im = (int)(rest / 784);   // b*3+n
  const int ci = kk / 9, tap = kk % 9;
  const int y = p / 28 + tap / 3 - 1, x = p % 28 + tap % 3 - 1;
  float v = 0.0f;
  if ((unsigned)y < 28u && (unsigned)x < 28u) {
    const int q = y * 28 + x;
    const int b = im / 3, n = im % 3;
    v = (ci < 512) ? ro[((long)b * 1536 + n * 512 + ci) * 784 + q]
                   : h[((long)im * 256 + (ci - 512)) * 784 + q];
  }
  dst[idx] = f2bf(v);
}

// ---------------------------------------------------------------------------
// In-place softmax over rows of 12544 bf16 (one block per row)
// ---------------------------------------------------------------------------
__global__ __launch_bounds__(256) void softmax_inplace(u16* __restrict__ buf)
{
  u16* ptr = buf + (long)blockIdx.x * 12544;
  uint4* p4 = (uint4*)ptr;          // 1568 x (8 bf16)
  const int t = threadIdx.x;
  __shared__ float red[4];
  float mx = -3.0e38f;
  for (int v = t; v < 1568; v += 256) {
    uint4 u = p4[v];
    const u32 w[4] = {u.x, u.y, u.z, u.w};
    #pragma unroll
    for (int q = 0; q < 4; ++q) {
      mx = fmaxf(mx, bf2f((u16)(w[q] & 0xFFFFu)));
      mx = fmaxf(mx, bf2f((u16)(w[q] >> 16)));
    }
  }
  #pragma unroll
  for (int o = 32; o > 0; o >>= 1) mx = fmaxf(mx, __shfl_xor(mx, o));
  if ((t & 63) == 0) red[t >> 6] = mx;
  __syncthreads();
  mx = fmaxf(fmaxf(red[0], red[1]), fmaxf(red[2], red[3]));

  float s = 0.0f;
  for (int v = t; v < 1568; v += 256) {
    uint4 u = p4[v];
    const u32 w[4] = {u.x, u.y, u.z, u.w};
    #pragma unroll
    for (int q = 0; q < 4; ++q) {
      s += __expf(bf2f((u16)(w[q] & 0xFFFFu)) - mx);
      s += __expf(bf2f((u16)(w[q] >> 16)) - mx);
    }
  }
  #pragma unroll
  for (int o = 32; o > 0; o >>= 1) s += __shfl_xor(s, o);
  __syncthreads();
  if ((t & 63) == 0) red[t >> 6] = s;
  __syncthreads();
  const float inv = 1.0f / (red[0] + red[1] + red[2] + red[3]);

  for (int v = t; v < 1568; v += 256) {
    uint4 u = p4[v];
    u32 w[4] = {u.x, u.y, u.z, u.w};
    #pragma unroll
    for (int q = 0; q < 4; ++q) {
      const float a = __expf(bf2f((u16)(w[q] & 0xFFFFu)) - mx) * inv;
      const float b = __expf(bf2f((u16)(w[q] >> 16)) - mx) * inv;
      w[q] = (u32)f2bf(a) | ((u32)f2bf(b) << 16);
    }
    p4[v] = make_uint4(w[0], w[1], w[2], w[3]);
  }
}

// ---------------------------------------------------------------------------
// Gated update: out = sig(f)*h*(1-sig(u)) + sig(u)*tanh(nv)
// ---------------------------------------------------------------------------
__global__ __launch_bounds__(256) void gating_kernel(
    const float* __restrict__ vals,  // [6][768][784]
    const float* __restrict__ h,     // [6][256][784]
    float* __restrict__ out)         // [6][256][784]
{
  const long total = 6L * 256 * 784;
  const long idx = (long)blockIdx.x * 256 + threadIdx.x;
  if (idx >= total) return;
  const int p = (int)(idx % 784);
  const long rest = idx / 784;
  const int cs = (int)(rest % 256);
  const int im = (int)(rest / 256);
  const float* vb = vals + (long)im * 768 * 784;
  const float fg = vb[(long)cs * 784 + p];
  const float ug = vb[(long)(256 + cs) * 784 + p];
  const float nv = vb[(long)(512 + cs) * 784 + p];
  const float sf = 1.0f / (1.0f + __expf(-fg));
  const float su = 1.0f / (1.0f + __expf(-ug));
  const float e2 = __expf(2.0f * nv);
  const float tv = (e2 - 1.0f) / (e2 + 1.0f);
  const float hv = h[idx];
  out[idx] = sf * hv * (1.0f - su) + su * tv;
}

__global__ __launch_bounds__(256) void fill_sentinel(float* p, long n) {
  const long i = (long)blockIdx.x * 256 + threadIdx.x;
  if (i < n) p[i] = 12345.0f;
}

// ---------------------------------------------------------------------------
extern "C" void kernel_launch(void* const* d_in, const int* in_sizes, int n_in,
                              void* d_out, int out_size, void* d_ws, size_t ws_size,
                              hipStream_t stream) {
  const float* f16 = (const float*)d_in[0];   // [2,1024,28,28]
  const float* mk  = (const float*)d_in[1];   // [2,64,16,28,28]
  const float* mv  = (const float*)d_in[2];   // [2,3,512,16,28,28]
  const float* hin = (const float*)d_in[3];   // [2,3,256,28,28]
  const float* w1  = (const float*)d_in[4];   // [512,1024,1,1]
  const float* b1  = (const float*)d_in[5];
  const float* w2  = (const float*)d_in[6];   // [64,512,3,3]
  const float* b2  = (const float*)d_in[7];
  const float* wt  = (const float*)d_in[8];   // [768,768,3,3]
  const float* bt  = (const float*)d_in[9];
  float* out = (float*)d_out;

  char* base = (char*)d_ws;
  size_t off = 0;
  auto alloc = [&](size_t bytes) -> char* {
    char* p = base + off;
    off = (off + bytes + 255) & ~(size_t)255;
    return p;
  };
  u16*   f16T    = (u16*)  alloc(2UL*784*1024*2);     // B-op of conv1 GEMM
  float* out1    = (float*)alloc(2UL*512*784*4);      // conv1 result
  float* qk      = (float*)alloc(2UL*64*784*4);       // conv2 result
  float* qkT     = (float*)alloc(2UL*784*64*4);       // A-op of logits GEMM
  u16*   mkT     = (u16*)  alloc(2UL*12544*64*2);     // B-op of logits GEMM
  char*  cv      =         alloc(2UL*784*4608*2);     // colT2 bf16, later vals f32 (same size)
  u16*   colT2   = (u16*)cv;
  float* vals    = (float*)cv;
  u16*   logaff  = (u16*)  alloc(2UL*784*12544*2);    // logits -> aff, in place
  float* readout = (float*)alloc(2UL*1536*784*4);
  u16*   colTE   = (u16*)  alloc(6UL*784*6912*2);
  if (off > ws_size) {   // workspace too small: emit distinguishable sentinel
    fill_sentinel<<<4704, 256, 0, stream>>>(out, (long)out_size);
    return;
  }

  // 1) layout transposes (fp32 -> bf16 where operand feeds GEMM B-side)
  transpose_k<true ><<<dim3(25, 32, 2), 256, 0, stream>>>(f16, f16T, 1024, 784, 1024L*784, 784L*1024);
  transpose_k<true ><<<dim3(392, 2, 2), 256, 0, stream>>>(mk, mkT, 64, 12544, 64L*12544, 12544L*64);
  // 2) conv1 (1x1): out1 = w1*f16 + b1       M=512 N=784 K=1024
  gemm_kernel<true, false><<<dim3(4, 7, 2), 256, 0, stream>>>(
      w1, f16T, out1, b1, 512, 784, 1024, 0, 784L*1024, 512L*784, 1.0f);
  // 3) conv2 (3x3) via im2col:  qk = w2 (*) out1 + b2   M=64 N=784 K=4608
  im2col_3x3<<<28224, 256, 0, stream>>>(out1, colT2, 512, 2);
  gemm_kernel<true, false><<<dim3(1, 7, 2), 256, 0, stream>>>(
      w2, colT2, qk, b2, 64, 784, 4608, 0, 784L*4608, 64L*784, 1.0f);
  transpose_k<false><<<dim3(25, 2, 2), 256, 0, stream>>>(qk, qkT, 64, 784, 64L*784, 784L*64);
  // 4) logits^T[p][m] = qk.mk/8 -> bf16      M=784 N=12544 K=64
  gemm_kernel<false, true><<<dim3(7, 98, 2), 256, 0, stream>>>(
      qkT, mkT, logaff, nullptr, 784, 12544, 64, 784L*64, 12544L*64, 784L*12544, 0.125f);
  // 5) softmax over memory axis (rows of 12544), in place
  softmax_inplace<<<1568, 256, 0, stream>>>(logaff);
  // 6) readout[(n,c)][p] = mv*aff            M=1536 N=784 K=12544
  gemm_kernel<false, false><<<dim3(12, 7, 2), 256, 0, stream>>>(
      mv, logaff, readout, nullptr, 1536, 784, 12544, 1536L*12544, 784L*12544, 1536L*784, 1.0f);
  // 7) transform conv (3x3) on concat([readout,h]) via im2col
  im2col_concat<<<127008, 256, 0, stream>>>(readout, hin, colTE);
  gemm_kernel<true, false><<<dim3(6, 7, 6), 256, 0, stream>>>(
      wt, colTE, vals, bt, 768, 784, 6912, 0, 784L*6912, 768L*784, 1.0f);
  // 8) gated recurrent update -> d_out
  gating_kernel<<<4704, 256, 0, stream>>>(vals, hin, out);
}

// Round 2
// 421.936 us; speedup vs baseline: 2.7180x; 2.7180x over previous
//
#include <hip/hip_runtime.h>

typedef unsigned short u16;
typedef unsigned int u32;
typedef float f32x4v __attribute__((ext_vector_type(4)));
typedef __bf16 bf16x8 __attribute__((ext_vector_type(8)));

__device__ __forceinline__ u16 f2bf(float f) {
  u32 u = __builtin_bit_cast(u32, f);
  u32 r = (u + 0x7FFFu + ((u >> 16) & 1u)) >> 16;  // RNE
  return (u16)r;
}
__device__ __forceinline__ float bf2f(u16 h) {
  return __builtin_bit_cast(float, (u32)h << 16);
}

// ---------------------------------------------------------------------------
// MFMA GEMM, 128x128 tile, BK=32, reg-prefetch double buffer, split-K.
//   C = A(MxK) * B(NxK)^T ; z = zb*S + s ; k-range [s*Kc, (s+1)*Kc)
// ASRC: 0 = A fp32 (convert in stage), 1 = A bf16.
// OUT : 0 = fp32 partial at C + z*strC (no bias/scale)
//       2 = bf16 final at C + zb*strC (scale, optional bias)
// ---------------------------------------------------------------------------
template <int ASRC, int OUT, bool HAS_BIAS>
__global__ __launch_bounds__(256) void gemm128(
    const void* __restrict__ A_, const u16* __restrict__ B,
    void* __restrict__ C, const float* __restrict__ bias,
    int M, int N, int Kc, int fullK, int S,
    long strA, long strB, long strC, float scale)
{
  constexpr int PAD = 8;
  __shared__ u16 sA[128][32 + PAD];
  __shared__ u16 sB[128][32 + PAD];
  const int t = threadIdx.x, lane = t & 63, wave = t >> 6;
  const int wr = (wave >> 1) * 64, wc = (wave & 1) * 64;
  const int m0 = blockIdx.x * 128, n0 = blockIdx.y * 128;
  const int z = blockIdx.z, zb = z / S, s = z - zb * S;
  const int kbeg = s * Kc;
  const int srow = t >> 1, sk = (t & 1) * 16;
  const int lr = lane & 15, lk = (lane >> 4) * 8;
  const int gr = m0 + srow, gn = n0 + srow;
  const bool va = (gr < M), vb = (gn < N);

  const float* Af = (const float*)A_ + (long)zb * strA + (long)(va ? gr : 0) * fullK + kbeg + sk;
  const u16*   Ah = (const u16*)A_   + (long)zb * strA + (long)(va ? gr : 0) * fullK + kbeg + sk;
  const u16*   Bh = B + (long)zb * strB + (long)(vb ? gn : 0) * fullK + kbeg + sk;

  float4 pa[4];
  uint4 pah[2], pb[2];
  const uint4 z4 = make_uint4(0, 0, 0, 0);

  auto loadT = [&](int k0) {
    if constexpr (ASRC == 0) {
      const float4* p = (const float4*)(Af + k0);
      #pragma unroll
      for (int q = 0; q < 4; ++q) pa[q] = p[q];
      if (!va) {
        #pragma unroll
        for (int q = 0; q < 4; ++q) pa[q] = make_float4(0, 0, 0, 0);
      }
    } else {
      const uint4* p = (const uint4*)(Ah + k0);
      pah[0] = p[0]; pah[1] = p[1];
      if (!va) { pah[0] = z4; pah[1] = z4; }
    }
    const uint4* q = (const uint4*)(Bh + k0);
    pb[0] = q[0]; pb[1] = q[1];
    if (!vb) { pb[0] = z4; pb[1] = z4; }
  };

  auto storeT = [&]() {
    if constexpr (ASRC == 0) {
      u16 us[16];
      #pragma unroll
      for (int q = 0; q < 4; ++q) {
        us[4*q+0] = f2bf(pa[q].x); us[4*q+1] = f2bf(pa[q].y);
        us[4*q+2] = f2bf(pa[q].z); us[4*q+3] = f2bf(pa[q].w);
      }
      *(uint4*)&sA[srow][sk]     = *(uint4*)&us[0];
      *(uint4*)&sA[srow][sk + 8] = *(uint4*)&us[8];
    } else {
      *(uint4*)&sA[srow][sk]     = pah[0];
      *(uint4*)&sA[srow][sk + 8] = pah[1];
    }
    *(uint4*)&sB[srow][sk]     = pb[0];
    *(uint4*)&sB[srow][sk + 8] = pb[1];
  };

  f32x4v acc[4][4] = {};
  const int niter = Kc >> 5;
  loadT(0);
  for (int it = 0; it < niter; ++it) {
    __syncthreads();
    storeT();
    __syncthreads();
    if (it + 1 < niter) loadT((it + 1) << 5);
    bf16x8 af[4], bfr[4];
    #pragma unroll
    for (int i = 0; i < 4; ++i) af[i] = *(const bf16x8*)&sA[wr + i*16 + lr][lk];
    #pragma unroll
    for (int j = 0; j < 4; ++j) bfr[j] = *(const bf16x8*)&sB[wc + j*16 + lr][lk];
    #pragma unroll
    for (int i = 0; i < 4; ++i) {
      #pragma unroll
      for (int j = 0; j < 4; ++j)
        acc[i][j] = __builtin_amdgcn_mfma_f32_16x16x32_bf16(af[i], bfr[j], acc[i][j], 0, 0, 0);
    }
  }

  // epilogue: D lane l reg r -> row=(l>>4)*4+r, col=l&15
  const int lq = (lane >> 4) * 4;
  if constexpr (OUT == 0) {
    float* Cp = (float*)C + (long)z * strC;
    #pragma unroll
    for (int i = 0; i < 4; ++i)
      #pragma unroll
      for (int r = 0; r < 4; ++r) {
        const int row = m0 + wr + i*16 + lq + r;
        if (row >= M) continue;
        #pragma unroll
        for (int j = 0; j < 4; ++j) {
          const int col = n0 + wc + j*16 + lr;
          if (col < N) Cp[(long)row * N + col] = acc[i][j][r];
        }
      }
  } else {
    u16* Cp = (u16*)C + (long)zb * strC;
    #pragma unroll
    for (int i = 0; i < 4; ++i)
      #pragma unroll
      for (int r = 0; r < 4; ++r) {
        const int row = m0 + wr + i*16 + lq + r;
        if (row >= M) continue;
        const float bv = HAS_BIAS ? bias[row] : 0.0f;
        #pragma unroll
        for (int j = 0; j < 4; ++j) {
          const int col = n0 + wc + j*16 + lr;
          if (col < N) Cp[(long)row * N + col] = f2bf((acc[i][j][r] + bv) * scale);
        }
      }
  }
}

// ---------------------------------------------------------------------------
// Implicit-GEMM 3x3 SAME conv on 28x28 (N=784 pixels).
//   Aw  : bf16 [M][9*Cin]  tap-major reordered weights
//   Bimg: bf16 [Z][784][Cin] channel-last image
//   z = zb*S + s ; taps [s*(9/S), ...) ; OUT=0 fp32 partial at C + z*strC
// ---------------------------------------------------------------------------
template <int OUT>
__global__ __launch_bounds__(256) void conv3g(
    const u16* __restrict__ Aw, const u16* __restrict__ Bimg,
    float* __restrict__ C, int M, int Cin, int S, long strB, long strC)
{
  constexpr int PAD = 8;
  __shared__ u16 sA[128][32 + PAD];
  __shared__ u16 sB[128][32 + PAD];
  const int t = threadIdx.x, lane = t & 63, wave = t >> 6;
  const int wr = (wave >> 1) * 64, wc = (wave & 1) * 64;
  const int m0 = blockIdx.x * 128, n0 = blockIdx.y * 128;
  const int z = blockIdx.z, zb = z / S, s = z - zb * S;
  const int tps = 9 / S, tbeg = s * tps;
  const int kiters = Cin >> 5;
  const int niter = tps * kiters;
  const int srow = t >> 1, sk = (t & 1) * 16;
  const int lr = lane & 15, lk = (lane >> 4) * 8;
  const int gr = m0 + srow, gn = n0 + srow;   // gn = pixel p
  const bool va = (gr < M), vbp = (gn < 784);
  const int py = gn / 28, px = gn % 28;

  const u16* Arow  = Aw + (long)(va ? gr : 0) * (9 * Cin) + sk;
  const u16* Bbase = Bimg + (long)zb * strB + sk;

  uint4 pah[2], pb[2];
  const uint4 z4 = make_uint4(0, 0, 0, 0);

  auto loadT = [&](int tap, int k0) {
    const uint4* p = (const uint4*)(Arow + tap * Cin + k0);
    pah[0] = p[0]; pah[1] = p[1];
    if (!va) { pah[0] = z4; pah[1] = z4; }
    const int dy = tap / 3 - 1, dx = tap % 3 - 1;
    const bool v = vbp && (unsigned)(py + dy) < 28u && (unsigned)(px + dx) < 28u;
    const int q = gn + dy * 28 + dx;
    const uint4* b = (const uint4*)(Bbase + (long)(v ? q : 0) * Cin + k0);
    pb[0] = b[0]; pb[1] = b[1];
    if (!v) { pb[0] = z4; pb[1] = z4; }
  };

  f32x4v acc[4][4] = {};
  int tap = tbeg, k0 = 0;
  loadT(tap, k0);
  for (int it = 0; it < niter; ++it) {
    __syncthreads();
    *(uint4*)&sA[srow][sk]     = pah[0];
    *(uint4*)&sA[srow][sk + 8] = pah[1];
    *(uint4*)&sB[srow][sk]     = pb[0];
    *(uint4*)&sB[srow][sk + 8] = pb[1];
    __syncthreads();
    int nk = k0 + 32, nt = tap;
    if (nk == Cin) { nk = 0; ++nt; }
    if (it + 1 < niter) loadT(nt, nk);
    bf16x8 af[4], bfr[4];
    #pragma unroll
    for (int i = 0; i < 4; ++i) af[i] = *(const bf16x8*)&sA[wr + i*16 + lr][lk];
    #pragma unroll
    for (int j = 0; j < 4; ++j) bfr[j] = *(const bf16x8*)&sB[wc + j*16 + lr][lk];
    #pragma unroll
    for (int i = 0; i < 4; ++i) {
      #pragma unroll
      for (int j = 0; j < 4; ++j)
        acc[i][j] = __builtin_amdgcn_mfma_f32_16x16x32_bf16(af[i], bfr[j], acc[i][j], 0, 0, 0);
    }
    tap = nt; k0 = nk;
  }

  float* Cp = C + (long)z * strC;
  const int lq = (lane >> 4) * 4;
  #pragma unroll
  for (int i = 0; i < 4; ++i)
    #pragma unroll
    for (int r = 0; r < 4; ++r) {
      const int row = m0 + wr + i*16 + lq + r;
      if (row >= M) continue;
      #pragma unroll
      for (int j = 0; j < 4; ++j) {
        const int col = n0 + wc + j*16 + lr;
        if (col < 784) Cp[(long)row * 784 + col] = acc[i][j][r];
      }
    }
}

// ---------------------------------------------------------------------------
// Transpose fp32 [z][R][C] -> bf16 out[z*strOutZ + c*ldOut + colOff + r]
// ---------------------------------------------------------------------------
__global__ __launch_bounds__(256) void transpose_bf(
    const float* __restrict__ in, u16* __restrict__ out,
    int R, int C, long strOutZ, int ldOut, int colOff)
{
  __shared__ float tile[32][33];
  in  += (long)blockIdx.z * R * C;
  out += (long)blockIdx.z * strOutZ;
  const int c0 = blockIdx.x * 32, r0 = blockIdx.y * 32;
  const int tx = threadIdx.x & 31, ty = threadIdx.x >> 5;
  for (int i = ty; i < 32; i += 8) {
    const int r = r0 + i, c = c0 + tx;
    tile[i][tx] = (r < R && c < C) ? in[(long)r * C + c] : 0.0f;
  }
  __syncthreads();
  for (int i = ty; i < 32; i += 8) {
    const int r = r0 + tx, c = c0 + i;
    if (c < C && r < R)
      out[(long)c * ldOut + colOff + r] = f2bf(tile[tx][i]);
  }
}

// fp32 -> bf16 elementwise, 8 elems/thread (n must be multiple of 8)
__global__ __launch_bounds__(256) void convert_bf(
    const float* __restrict__ in, u16* __restrict__ out, long n8)
{
  const long i = (long)blockIdx.x * 256 + threadIdx.x;
  if (i >= n8) return;
  const float4* p = (const float4*)in + i * 2;
  const float4 a = p[0], b = p[1];
  u16 o[8] = {f2bf(a.x), f2bf(a.y), f2bf(a.z), f2bf(a.w),
              f2bf(b.x), f2bf(b.y), f2bf(b.z), f2bf(b.w)};
  ((uint4*)out)[i] = *(uint4*)o;
}

// weight reorder: dst[m][tap][c] = src[m][c][tap]  (bf16 out)
__global__ __launch_bounds__(256) void permute_w(
    const float* __restrict__ src, u16* __restrict__ dst, int M, int Cin)
{
  const long total = (long)M * 9 * Cin;
  const long idx = (long)blockIdx.x * 256 + threadIdx.x;
  if (idx >= total) return;
  const int c = (int)(idx % Cin);
  const int tap = (int)((idx / Cin) % 9);
  const int m = (int)(idx / ((long)9 * Cin));
  dst[idx] = f2bf(src[((long)m * Cin + c) * 9 + tap]);
}

// sum S fp32 partials (+optional bias per row) -> fp32, float4-vectorized
__global__ __launch_bounds__(256) void reduce_add(
    const float* __restrict__ parts, float* __restrict__ out,
    const float* __restrict__ bias, int S, long MN, int N, long total4)
{
  const long i4 = (long)blockIdx.x * 256 + threadIdx.x;
  if (i4 >= total4) return;
  const long MN4 = MN >> 2;
  const long zb = i4 / MN4, r = i4 - zb * MN4;
  f32x4v sum = {0, 0, 0, 0};
  for (int s = 0; s < S; ++s)
    sum += ((const f32x4v*)(parts + (zb * S + s) * MN))[r];
  if (bias) {
    const float bv = bias[(int)((r * 4) / N)];
    sum += (f32x4v){bv, bv, bv, bv};
  }
  ((f32x4v*)(out + zb * MN))[r] = sum;
}

// ---------------------------------------------------------------------------
// In-place softmax over rows of 12544 bf16 (one block per row)
// ---------------------------------------------------------------------------
__global__ __launch_bounds__(256) void softmax_inplace(u16* __restrict__ buf)
{
  u16* ptr = buf + (long)blockIdx.x * 12544;
  uint4* p4 = (uint4*)ptr;
  const int t = threadIdx.x;
  __shared__ float red[4];
  float mx = -3.0e38f;
  for (int v = t; v < 1568; v += 256) {
    uint4 u = p4[v];
    const u32 w[4] = {u.x, u.y, u.z, u.w};
    #pragma unroll
    for (int q = 0; q < 4; ++q) {
      mx = fmaxf(mx, bf2f((u16)(w[q] & 0xFFFFu)));
      mx = fmaxf(mx, bf2f((u16)(w[q] >> 16)));
    }
  }
  #pragma unroll
  for (int o = 32; o > 0; o >>= 1) mx = fmaxf(mx, __shfl_xor(mx, o));
  if ((t & 63) == 0) red[t >> 6] = mx;
  __syncthreads();
  mx = fmaxf(fmaxf(red[0], red[1]), fmaxf(red[2], red[3]));

  float s = 0.0f;
  for (int v = t; v < 1568; v += 256) {
    uint4 u = p4[v];
    const u32 w[4] = {u.x, u.y, u.z, u.w};
    #pragma unroll
    for (int q = 0; q < 4; ++q) {
      s += __expf(bf2f((u16)(w[q] & 0xFFFFu)) - mx);
      s += __expf(bf2f((u16)(w[q] >> 16)) - mx);
    }
  }
  #pragma unroll
  for (int o = 32; o > 0; o >>= 1) s += __shfl_xor(s, o);
  __syncthreads();
  if ((t & 63) == 0) red[t >> 6] = s;
  __syncthreads();
  const float inv = 1.0f / (red[0] + red[1] + red[2] + red[3]);

  for (int v = t; v < 1568; v += 256) {
    uint4 u = p4[v];
    u32 w[4] = {u.x, u.y, u.z, u.w};
    #pragma unroll
    for (int q = 0; q < 4; ++q) {
      const float a = __expf(bf2f((u16)(w[q] & 0xFFFFu)) - mx) * inv;
      const float b = __expf(bf2f((u16)(w[q] >> 16)) - mx) * inv;
      w[q] = (u32)f2bf(a) | ((u32)f2bf(b) << 16);
    }
    p4[v] = make_uint4(w[0], w[1], w[2], w[3]);
  }
}

// ---------------------------------------------------------------------------
// Fused transform-reduce + gating. parts: [im*3+s][768][784] fp32 (S=3).
// out[im][cs][p] = sig(F)*h*(1-sig(U)) + sig(U)*tanh(NV)
// ---------------------------------------------------------------------------
__global__ __launch_bounds__(256) void treduce_gate(
    const float* __restrict__ parts, const float* __restrict__ bt,
    const float* __restrict__ h, float* __restrict__ out)
{
  const long i = (long)blockIdx.x * 256 + threadIdx.x;
  if (i >= 6L * 256 * 196) return;
  const int p4 = (int)(i % 196);
  const int rest = (int)(i / 196);
  const int cs = rest % 256, im = rest / 256;
  const long MN = 768L * 784;
  const f32x4v* P = (const f32x4v*)parts;
  f32x4v F = {0,0,0,0}, U = {0,0,0,0}, NV = {0,0,0,0};
  #pragma unroll
  for (int s = 0; s < 3; ++s) {
    const long b4 = ((long)(im * 3 + s) * MN) >> 2;
    F  += P[b4 + ((long)cs         * 784 >> 2) + p4];
    U  += P[b4 + ((long)(256 + cs) * 784 >> 2) + p4];
    NV += P[b4 + ((long)(512 + cs) * 784 >> 2) + p4];
  }
  const float bF = bt[cs], bU = bt[256 + cs], bN = bt[512 + cs];
  const f32x4v hv = ((const f32x4v*)h)[((long)(im * 256 + cs) * 784 >> 2) + p4];
  f32x4v o;
  #pragma unroll
  for (int q = 0; q < 4; ++q) {
    const float f = F[q] + bF, u = U[q] + bU, nv = NV[q] + bN;
    const float sf = 1.0f / (1.0f + __expf(-f));
    const float su = 1.0f / (1.0f + __expf(-u));
    const float e2 = __expf(2.0f * nv);
    const float tv = (e2 - 1.0f) / (e2 + 1.0f);
    o[q] = sf * hv[q] * (1.0f - su) + su * tv;
  }
  ((f32x4v*)out)[((long)(im * 256 + cs) * 784 >> 2) + p4] = o;
}

__global__ __launch_bounds__(256) void fill_sentinel(float* p, long n) {
  const long i = (long)blockIdx.x * 256 + threadIdx.x;
  if (i < n) p[i] = 12345.0f;
}

// ---------------------------------------------------------------------------
extern "C" void kernel_launch(void* const* d_in, const int* in_sizes, int n_in,
                              void* d_out, int out_size, void* d_ws, size_t ws_size,
                              hipStream_t stream) {
  const float* f16 = (const float*)d_in[0];   // [2,1024,28,28]
  const float* mk  = (const float*)d_in[1];   // [2,64,16,28,28]
  const float* mv  = (const float*)d_in[2];   // [2,3,512,16,28,28]
  const float* hin = (const float*)d_in[3];   // [2,3,256,28,28]
  const float* w1  = (const float*)d_in[4];   // [512,1024,1,1]
  const float* b1  = (const float*)d_in[5];
  const float* w2  = (const float*)d_in[6];   // [64,512,3,3]
  const float* b2  = (const float*)d_in[7];
  const float* wt  = (const float*)d_in[8];   // [768,768,3,3]
  const float* bt  = (const float*)d_in[9];
  float* out = (float*)d_out;

  char* base = (char*)d_ws;
  size_t off = 0;
  auto alloc = [&](size_t bytes) -> char* {
    char* p = base + off;
    off = (off + bytes + 255) & ~(size_t)255;
    return p;
  };
  u16*   w1b     = (u16*)  alloc(512UL*1024*2);
  u16*   w2R     = (u16*)  alloc(64UL*4608*2);
  u16*   wtR     = (u16*)  alloc(768UL*6912*2);
  u16*   f16T    = (u16*)  alloc(2UL*784*1024*2);
  u16*   mkT     = (u16*)  alloc(2UL*12544*64*2);
  float* out1    = (float*)alloc(2UL*512*784*4);
  u16*   out1T   = (u16*)  alloc(2UL*784*512*2);
  float* qk      = (float*)alloc(2UL*64*784*4);
  u16*   qkT     = (u16*)  alloc(2UL*784*64*2);
  u16*   logaff  = (u16*)  alloc(2UL*784*12544*2);
  float* readout = (float*)alloc(2UL*1536*784*4);
  u16*   concatT = (u16*)  alloc(6UL*784*768*2);
  float* parts   = (float*)alloc(18UL*768*784*4);   // shared partial pool (43.4 MB)
  const size_t base_need = off;
  u16* mvb = (u16*)alloc(2UL*1536*12544*2);          // optional (77 MB)
  const bool use_mvb = (off <= ws_size);
  if (base_need > ws_size) {
    fill_sentinel<<<4704, 256, 0, stream>>>(out, (long)out_size);
    return;
  }

  // --- operand prep (all bf16) ---
  convert_bf<<<256, 256, 0, stream>>>(w1, w1b, 65536);
  permute_w<<<1152, 256, 0, stream>>>(w2, w2R, 64, 512);
  permute_w<<<20736, 256, 0, stream>>>(wt, wtR, 768, 768);
  transpose_bf<<<dim3(25, 32, 2), 256, 0, stream>>>(f16, f16T, 1024, 784, 784L*1024, 1024, 0);
  transpose_bf<<<dim3(392, 2, 2), 256, 0, stream>>>(mk, mkT, 64, 12544, 12544L*64, 64, 0);
  if (use_mvb)
    convert_bf<<<18816, 256, 0, stream>>>(mv, mvb, 4816896);

  // --- conv1 (1x1): M=512 N=784 K=1024, split-K S=4 ---
  gemm128<1, 0, false><<<dim3(4, 7, 8), 256, 0, stream>>>(
      w1b, f16T, parts, nullptr, 512, 784, 256, 1024, 4, 0, 784L*1024, 512L*784, 1.0f);
  reduce_add<<<784, 256, 0, stream>>>(parts, out1, b1, 4, 512L*784, 784, 2L*512*196);
  transpose_bf<<<dim3(25, 16, 2), 256, 0, stream>>>(out1, out1T, 512, 784, 784L*512, 512, 0);

  // --- conv2 (3x3 implicit): M=64 Cin=512, split S=9 (1 tap/chunk) ---
  conv3g<0><<<dim3(1, 7, 18), 256, 0, stream>>>(
      w2R, out1T, parts, 64, 512, 9, 784L*512, 64L*784);
  reduce_add<<<98, 256, 0, stream>>>(parts, qk, b2, 9, 64L*784, 784, 2L*64*196);
  transpose_bf<<<dim3(25, 2, 2), 256, 0, stream>>>(qk, qkT, 64, 784, 784L*64, 64, 0);

  // --- logits: M=784 N=12544 K=64 -> bf16, scale 1/8 ---
  gemm128<1, 2, false><<<dim3(7, 98, 2), 256, 0, stream>>>(
      qkT, mkT, logaff, nullptr, 784, 12544, 64, 64, 1,
      784L*64, 12544L*64, 784L*12544, 0.125f);

  // --- softmax over memory axis ---
  softmax_inplace<<<1568, 256, 0, stream>>>(logaff);

  // --- readout: M=1536 N=784 K=12544, split-K S=4 ---
  if (use_mvb)
    gemm128<1, 0, false><<<dim3(12, 7, 8), 256, 0, stream>>>(
        mvb, logaff, parts, nullptr, 1536, 784, 3136, 12544, 4,
        1536L*12544, 784L*12544, 1536L*784, 1.0f);
  else
    gemm128<0, 0, false><<<dim3(12, 7, 8), 256, 0, stream>>>(
        mv, logaff, parts, nullptr, 1536, 784, 3136, 12544, 4,
        1536L*12544, 784L*12544, 1536L*784, 1.0f);
  reduce_add<<<2352, 256, 0, stream>>>(parts, readout, nullptr, 4, 1536L*784, 784, 2L*1536*196);

  // --- concat + transpose to channel-last bf16 [6][784][768] ---
  transpose_bf<<<dim3(25, 16, 6), 256, 0, stream>>>(readout, concatT, 512, 784, 784L*768, 768, 0);
  transpose_bf<<<dim3(25, 8, 6), 256, 0, stream>>>(hin, concatT, 256, 784, 784L*768, 768, 512);

  // --- transform conv (3x3 implicit): M=768 Cin=768, split S=3 (3 taps) ---
  conv3g<0><<<dim3(6, 7, 18), 256, 0, stream>>>(
      wtR, concatT, parts, 768, 768, 3, 784L*768, 768L*784);

  // --- fused reduce + gating -> d_out ---
  treduce_gate<<<1176, 256, 0, stream>>>(parts, bt, hin, out);
}